// Round 4
// baseline (228.023 us; speedup 1.0000x reference)
//
#include <hip/hip_runtime.h>
#include <hip/hip_bf16.h>
#include <stdint.h>

// B=4, S=8192, E=1024, heads=16 -> math collapses to:
//   Q = x @ W1[0:1024].T ; A = per-64-col-block softmax(Q/4) ; out = A @ W2.T
static constexpr int MTOT = 32768;
static constexpr int KD   = 1024;
static constexpr int ND   = 1024;

static constexpr int BM = 256, BN = 256, BK = 64;
static constexpr int NT = KD / BK;              // 16 K-tiles
static constexpr int BUF_BYTES = 65536;         // per-buffer: A 32K + B 32K
static constexpr int BOFF = 32768;              // B offset within buffer
static constexpr int HALF = 16384;              // one staging unit (128 rows x 64 cols bf16)

typedef __bf16 bf16x8 __attribute__((ext_vector_type(8)));
typedef float  f32x16 __attribute__((ext_vector_type(16)));

__device__ __forceinline__ unsigned short f2bf_rne(float f) {
  union { float f; uint32_t u; } c; c.f = f;
  uint32_t u = c.u;
  return (unsigned short)((u + 0x7fffu + ((u >> 16) & 1u)) >> 16);
}

__global__ void cast_f32_to_bf16(const float* __restrict__ src,
                                 unsigned short* __restrict__ dst, int n4) {
  int idx = blockIdx.x * blockDim.x + threadIdx.x;
  int stride = gridDim.x * blockDim.x;
  for (int i = idx; i < n4; i += stride) {
    float4 v = reinterpret_cast<const float4*>(src)[i];
    ushort4 o;
    o.x = f2bf_rne(v.x); o.y = f2bf_rne(v.y);
    o.z = f2bf_rne(v.z); o.w = f2bf_rne(v.w);
    reinterpret_cast<ushort4*>(dst)[i] = o;
  }
}

__device__ __forceinline__ void gload_lds16(const void* g, void* lds) {
  __builtin_amdgcn_global_load_lds(
      (const __attribute__((address_space(1))) unsigned int*)g,
      (__attribute__((address_space(3))) unsigned int*)lds, 16, 0, 0);
}

// 256x256 tile, BK=64, 8 waves (2Mx4N), double-buffered 128 KiB LDS,
// 4-phase schedule, counted vmcnt, 32x32x16 MFMA, ks-outer ordering,
// single barrier per phase (P4 keeps the post-vmcnt rendezvous barrier).
template <int SOFTMAX>
__global__ __launch_bounds__(512, 2)
void gemm8(const unsigned short* __restrict__ A,
           const unsigned short* __restrict__ Bm,
           void* __restrict__ Cout) {
  extern __shared__ __align__(16) char ldsc[];

  const int tid  = threadIdx.x;
  const int lane = tid & 63;
  const int wid  = tid >> 6;
  const int wm = wid >> 2, wn = wid & 3;       // wave tile: 128 rows x 64 cols
  const int l31 = lane & 31;
  const int hi  = lane >> 5;
  const int swz = (lane & 7) << 4;             // read-side XOR (row&7 == lane&7)

  // T1: bijective XCD swizzle (512 blocks, 8 XCDs, 64 blocks/chunk).
  const int bid0 = blockIdx.x;
  const int bid  = ((bid0 & 7) << 6) | (bid0 >> 3);
  const int brow = (bid >> 2) * BM;
  const int bcol = (bid & 3) * BN;

  // staging: linear LDS dest + inverse-swizzled global src (rule #21).
  const int srow  = tid >> 3;
  const int sslot = (tid & 7) ^ (srow & 7);
  const unsigned short* gA = A  + (size_t)(brow + srow) * KD + sslot * 8;
  const unsigned short* gB = Bm + (size_t)(bcol + srow) * KD + sslot * 8;

  f32x16 acc[4][2] = {};
  bf16x8 a0[2][4], a1[2][4], bA[4], bB[4];

  auto STAGE = [&](const unsigned short* g, int h, int kt, int b, int opOff) {
    const unsigned short* gu = g + (size_t)(h * 128) * KD + kt * BK;
    char* du = ldsc + b * BUF_BYTES + opOff + h * HALF + (wid << 10);
    gload_lds16(gu, du);
    gload_lds16(gu + (size_t)64 * KD, du + 8192);
  };

  // A frag (32x32x16): row = mg*32 + (lane&31), k = hi*8 + j, kstep ks:
  //   byte = (ks*32 + hi*16) ^ swz
  auto rdA = [&](int b, bf16x8 (*dst)[4], int mgBase) {
    const char* base = ldsc + b * BUF_BYTES + wm * HALF;
    #pragma unroll
    for (int i = 0; i < 2; ++i) {
      const int r = (mgBase + i) * 32 + l31;
      #pragma unroll
      for (int ks = 0; ks < 4; ++ks)
        dst[i][ks] = *(const bf16x8*)(base + (r << 7) +
                       ((ks * 32 + hi * 16) ^ swz));
    }
  };
  auto rdB = [&](int b, bf16x8* dst, int ng) {
    const char* base = ldsc + b * BUF_BYTES + BOFF + (wn >> 1) * HALF;
    const int r = (wn & 1) * 64 + ng * 32 + l31;
    #pragma unroll
    for (int ks = 0; ks < 4; ++ks)
      dst[ks] = *(const bf16x8*)(base + (r << 7) +
                   ((ks * 32 + hi * 16) ^ swz));
  };
  // ks-outer: adjacent MFMAs target different accumulators.
  auto MFMA8 = [&](int mgBase, int ng, bf16x8 (*af)[4], bf16x8* bf) {
    #pragma unroll
    for (int ks = 0; ks < 4; ++ks)
      #pragma unroll
      for (int i = 0; i < 2; ++i)
        acc[mgBase + i][ng] = __builtin_amdgcn_mfma_f32_32x32x16_bf16(
            af[i][ks], bf[ks], acc[mgBase + i][ng], 0, 0, 0);
  };

  // --- prologue: tile0 (4 units) + A halves of tile1 ---
  STAGE(gA, 0, 0, 0, 0);    STAGE(gA, 1, 0, 0, 0);
  STAGE(gB, 0, 0, 0, BOFF); STAGE(gB, 1, 0, 0, BOFF);
  STAGE(gA, 0, 1, 1, 0);    STAGE(gA, 1, 1, 1, 0);
  asm volatile("s_waitcnt vmcnt(4)" ::: "memory");   // tile0 landed for all my loads
  __builtin_amdgcn_s_barrier();                      // ...and everyone else's
  rdB(0, bA, 0);                                     // ng0 of tile 0

  for (int T = 0; T < NT; ++T) {
    const int cur = T & 1, nxt = cur ^ 1;
    const int tp1 = (T + 1 < NT) ? T + 1 : NT - 1;
    const int tp2 = (T + 2 < NT) ? T + 2 : NT - 1;

    // P1: (mg0-1, ng0)
    rdA(cur, a0, 0);
    STAGE(gB, 0, tp1, nxt, BOFF);
    asm volatile("s_waitcnt lgkmcnt(0)" ::: "memory");
    __builtin_amdgcn_s_setprio(1);
    MFMA8(0, 0, a0, bA);
    __builtin_amdgcn_s_setprio(0);
    __builtin_amdgcn_s_barrier();

    // P2: (mg2-3, ng0)
    rdA(cur, a1, 2);
    STAGE(gB, 1, tp1, nxt, BOFF);
    asm volatile("s_waitcnt lgkmcnt(0)" ::: "memory");
    __builtin_amdgcn_s_setprio(1);
    MFMA8(2, 0, a1, bA);
    __builtin_amdgcn_s_setprio(0);
    __builtin_amdgcn_s_barrier();

    // P3: (mg2-3, ng1)
    rdB(cur, bB, 1);
    STAGE(gA, 0, tp2, cur, 0);       // cur.A0: reads retired at P1's lgkmcnt(0)
    asm volatile("s_waitcnt lgkmcnt(0)" ::: "memory");
    __builtin_amdgcn_s_setprio(1);
    MFMA8(2, 1, a1, bB);
    __builtin_amdgcn_s_setprio(0);
    __builtin_amdgcn_s_barrier();

    // P4: (mg0-1, ng1); per-K-tile counted vmcnt + cross-wave rendezvous
    STAGE(gA, 1, tp2, cur, 0);
    asm volatile("s_waitcnt vmcnt(4)" ::: "memory"); // tile T+1 fully landed (mine)
    __builtin_amdgcn_s_barrier();                    // ...and all other waves'
    rdB(nxt, bA, 0);                 // next tile ng0; overlaps MFMA below
    __builtin_amdgcn_s_setprio(1);
    MFMA8(0, 1, a0, bB);
    __builtin_amdgcn_s_setprio(0);
    __builtin_amdgcn_s_barrier();
  }

  // C/D layout (32x32): col = lane&31, row = (reg&3) + 8*(reg>>2) + 4*hi
  if constexpr (SOFTMAX) {
    unsigned short* attn = reinterpret_cast<unsigned short*>(Cout);
    constexpr float CEXP = 0.25f * 1.44269504088896340736f; // log2(e)/4
    #pragma unroll
    for (int mg = 0; mg < 4; ++mg) {
      #pragma unroll
      for (int reg = 0; reg < 16; ++reg) {
        const int row = brow + wm * 128 + mg * 32 +
                        (reg & 3) + 8 * (reg >> 2) + 4 * hi;
        float v0 = acc[mg][0][reg], v1 = acc[mg][1][reg];
        float mx = fmaxf(v0, v1);
        #pragma unroll
        for (int s = 1; s < 32; s <<= 1) mx = fmaxf(mx, __shfl_xor(mx, s, 64));
        float p0 = exp2f((v0 - mx) * CEXP);
        float p1 = exp2f((v1 - mx) * CEXP);
        float sm = p0 + p1;
        #pragma unroll
        for (int s = 1; s < 32; s <<= 1) sm += __shfl_xor(sm, s, 64);
        const float inv = 1.0f / sm;
        unsigned short* dst = attn + (size_t)row * ND + (bcol + wn * 64 + l31);
        dst[0]  = f2bf_rne(p0 * inv);
        dst[32] = f2bf_rne(p1 * inv);
      }
    }
  } else {
    float* Cf = reinterpret_cast<float*>(Cout);
    #pragma unroll
    for (int mg = 0; mg < 4; ++mg) {
      #pragma unroll
      for (int ng = 0; ng < 2; ++ng) {
        #pragma unroll
        for (int reg = 0; reg < 16; ++reg) {
          const int row = brow + wm * 128 + mg * 32 +
                          (reg & 3) + 8 * (reg >> 2) + 4 * hi;
          Cf[(size_t)row * ND + (bcol + wn * 64 + ng * 32 + l31)] =
              acc[mg][ng][reg];
        }
      }
    }
  }
}

extern "C" void kernel_launch(void* const* d_in, const int* in_sizes, int n_in,
                              void* d_out, int out_size, void* d_ws, size_t ws_size,
                              hipStream_t stream) {
  const float* x  = (const float*)d_in[0];   // [4,8192,1024] f32
  const float* W1 = (const float*)d_in[1];   // [3072,1024]  f32 (rows 0..1023 = Wq)
  const float* W2 = (const float*)d_in[2];   // [1024,1024]  f32
  float* out = (float*)d_out;

  char* ws = (char*)d_ws;
  unsigned short* xb   = (unsigned short*)(ws);
  unsigned short* w1b  = (unsigned short*)(ws + (size_t)67108864);
  unsigned short* w2b  = (unsigned short*)(ws + (size_t)69206016);
  unsigned short* attn = (unsigned short*)(ws + (size_t)71303168);

  hipFuncSetAttribute(reinterpret_cast<const void*>(gemm8<1>),
                      hipFuncAttributeMaxDynamicSharedMemorySize, 131072);
  hipFuncSetAttribute(reinterpret_cast<const void*>(gemm8<0>),
                      hipFuncAttributeMaxDynamicSharedMemorySize, 131072);

  cast_f32_to_bf16<<<2048, 256, 0, stream>>>(x,  xb,  MTOT * KD / 4);
  cast_f32_to_bf16<<<512,  256, 0, stream>>>(W1, w1b, KD * KD / 4);
  cast_f32_to_bf16<<<512,  256, 0, stream>>>(W2, w2b, KD * KD / 4);

  const int nblk = (MTOT / BM) * (ND / BN);   // 128 * 4 = 512
  gemm8<1><<<nblk, 512, 131072, stream>>>(xb, w1b, (void*)attn);
  gemm8<0><<<nblk, 512, 131072, stream>>>(attn, w2b, (void*)out);
}